// Round 1
// baseline (432.598 us; speedup 1.0000x reference)
//
#include <hip/hip_runtime.h>

// ---------------------------------------------------------------------------
// Mamba block on MI355X. Shapes fixed by the reference:
//   B=8, L=1024, D_MODEL=512, D_INNER=1024, D2=512, DT_RANK=32, N_STATE=16,
//   K_CONV=4, HIDDEN=2048.  M = B*L = 8192 rows everywhere.
// All activations kept in (b, l, channel) row-major layout so every matmul is
// A(M,K) x W(N,K)^T with K contiguous.
// ---------------------------------------------------------------------------

#define MROWS 8192
#define LSEQ 1024
#define DMODEL 512
#define DINNER 1024
#define D2 512
#define NSTATE 16
#define HIDDEN 2048
#define NCHUNK 16
#define LCHUNK 64

typedef unsigned short ushortx;
typedef short short8 __attribute__((ext_vector_type(8)));
typedef float floatx4 __attribute__((ext_vector_type(4)));

__device__ __forceinline__ unsigned short f2bf(float f) {
    unsigned int u = __float_as_uint(f);
    u = (u + 0x7fffu + ((u >> 16) & 1u)) >> 16;
    return (unsigned short)u;
}

// ---------------------------------------------------------------------------
// Weight fp32 -> bf16 conversion (all 6 matmul weights in one kernel)
// sizes: in_proj 524288 | x_proj 32768 | dt_proj 16384 | out_proj 524288
//        fc1 1048576 | fc2 1048576   (total 3194880)
// ---------------------------------------------------------------------------
__global__ __launch_bounds__(256) void cvt_weights(
    const float* __restrict__ w0, const float* __restrict__ w1,
    const float* __restrict__ w2, const float* __restrict__ w3,
    const float* __restrict__ w4, const float* __restrict__ w5,
    unsigned short* __restrict__ o0, unsigned short* __restrict__ o1,
    unsigned short* __restrict__ o2, unsigned short* __restrict__ o3,
    unsigned short* __restrict__ o4, unsigned short* __restrict__ o5)
{
    int i = blockIdx.x * 256 + threadIdx.x;
    if (i < 524288)            o0[i]           = f2bf(w0[i]);
    else if (i < 557056)       o1[i - 524288]  = f2bf(w1[i - 524288]);
    else if (i < 573440)       o2[i - 557056]  = f2bf(w2[i - 557056]);
    else if (i < 1097728)      o3[i - 573440]  = f2bf(w3[i - 573440]);
    else if (i < 2146304)      o4[i - 1097728] = f2bf(w4[i - 1097728]);
    else if (i < 3194880)      o5[i - 2146304] = f2bf(w5[i - 2146304]);
}

// ---------------------------------------------------------------------------
// LayerNorm over 512 channels; one block (256 thr) per row; bf16 output.
// ---------------------------------------------------------------------------
__global__ __launch_bounds__(256) void ln_kernel(
    const float* __restrict__ x, const float* __restrict__ w,
    const float* __restrict__ b, unsigned short* __restrict__ out)
{
    int row = blockIdx.x;
    int tid = threadIdx.x;
    const float* xr = x + (size_t)row * DMODEL;
    float2 v = ((const float2*)xr)[tid];
    float s = v.x + v.y;
    float ss = v.x * v.x + v.y * v.y;
    #pragma unroll
    for (int off = 32; off > 0; off >>= 1) {
        s += __shfl_down(s, off);
        ss += __shfl_down(ss, off);
    }
    __shared__ float red[10];
    int wv = tid >> 6, ln = tid & 63;
    if (ln == 0) { red[wv] = s; red[wv + 4] = ss; }
    __syncthreads();
    if (tid == 0) {
        float S = red[0] + red[1] + red[2] + red[3];
        float SS = red[4] + red[5] + red[6] + red[7];
        float mean = S * (1.f / DMODEL);
        float var = SS * (1.f / DMODEL) - mean * mean;
        red[8] = mean;
        red[9] = rsqrtf(var + 1e-5f);
    }
    __syncthreads();
    float mean = red[8], rstd = red[9];
    float2 wv2 = ((const float2*)w)[tid];
    float2 bv2 = ((const float2*)b)[tid];
    unsigned short* o = out + (size_t)row * DMODEL + tid * 2;
    o[0] = f2bf((v.x - mean) * rstd * wv2.x + bv2.x);
    o[1] = f2bf((v.y - mean) * rstd * wv2.y + bv2.y);
}

// ---------------------------------------------------------------------------
// bf16 MFMA GEMM:  C(M,N) = A(M,K) * W(N,K)^T   (both row-major, bf16 in,
// fp32 accumulate).  128x128 block tile, BK=32, 256 threads = 4 waves,
// each wave a 64x64 quadrant as 4x4 tiles of 16x16x32 MFMA.
// Epilogue modes fuse bias / residual / softplus / gelu / bf16-store.
// ---------------------------------------------------------------------------
#define M_F32 0
#define M_F32_BF16 1
#define M_SOFTPLUS_F32 2
#define M_RES_F32 3
#define M_GELU_BF16 4
#define M_BIAS_RES_F32 5

template <int MODE>
__global__ __launch_bounds__(256) void gemm_bf16(
    const unsigned short* __restrict__ A, int lda,
    const unsigned short* __restrict__ B, int ldb,
    int M, int N, int K,
    float* __restrict__ outF, unsigned short* __restrict__ outB, int ldc,
    const float* __restrict__ bias, const float* __restrict__ res)
{
    __shared__ unsigned short sA[128 * 32];
    __shared__ unsigned short sB[128 * 32];
    int tid = threadIdx.x;
    int lane = tid & 63;
    int wave = tid >> 6;
    int m0 = blockIdx.x * 128;
    int n0 = blockIdx.y * 128;
    int wm = (wave & 1) * 64;
    int wn = (wave >> 1) * 64;
    int lq = lane >> 4;      // quad 0..3
    int lr = lane & 15;      // row-in-tile 0..15

    floatx4 zero4 = {0.f, 0.f, 0.f, 0.f};
    floatx4 acc[4][4];
    #pragma unroll
    for (int i = 0; i < 4; i++)
        #pragma unroll
        for (int j = 0; j < 4; j++) acc[i][j] = zero4;

    for (int k0 = 0; k0 < K; k0 += 32) {
        // stage 128x32 bf16 tiles of A and B (16 KB total, uint4 copies)
        #pragma unroll
        for (int q = 0; q < 2; q++) {
            int e = q * 2048 + tid * 8;       // element in tile
            int row = e >> 5;
            int col = e & 31;
            int gm = m0 + row;                // M always multiple of 128 here
            *(uint4*)(&sA[e]) = *(const uint4*)(&A[(size_t)gm * lda + k0 + col]);
            int gn = n0 + row; gn = gn < N ? gn : N - 1;
            *(uint4*)(&sB[e]) = *(const uint4*)(&B[(size_t)gn * ldb + k0 + col]);
        }
        __syncthreads();

        short8 af[4], bfr[4];
        #pragma unroll
        for (int i = 0; i < 4; i++) {
            af[i]  = *(const short8*)(&sA[(wm + i * 16 + lr) * 32 + lq * 8]);
            bfr[i] = *(const short8*)(&sB[(wn + i * 16 + lr) * 32 + lq * 8]);
        }
        #pragma unroll
        for (int i = 0; i < 4; i++)
            #pragma unroll
            for (int j = 0; j < 4; j++)
                acc[i][j] = __builtin_amdgcn_mfma_f32_16x16x32_bf16(
                    af[i], bfr[j], acc[i][j], 0, 0, 0);
        __syncthreads();
    }

    // epilogue: C/D layout col = lane&15, row = (lane>>4)*4 + reg
    #pragma unroll
    for (int j = 0; j < 4; j++) {
        int col = n0 + wn + j * 16 + lr;
        if (col >= N) continue;
        #pragma unroll
        for (int i = 0; i < 4; i++) {
            #pragma unroll
            for (int r = 0; r < 4; r++) {
                int rowm = m0 + wm + i * 16 + lq * 4 + r;
                float v = acc[i][j][r];
                size_t o = (size_t)rowm * ldc + col;
                if (MODE == M_F32) {
                    outF[o] = v;
                } else if (MODE == M_F32_BF16) {
                    outF[o] = v;
                    outB[o] = f2bf(v);
                } else if (MODE == M_SOFTPLUS_F32) {
                    float t = v + bias[col];
                    outF[o] = (t > 20.f) ? t : log1pf(__expf(t));
                } else if (MODE == M_RES_F32) {
                    outF[o] = v + res[o];
                } else if (MODE == M_GELU_BF16) {
                    float t = v + bias[col];
                    outB[o] = f2bf(0.5f * t * (1.f + erff(t * 0.70710678118f)));
                } else { // M_BIAS_RES_F32
                    outF[o] = v + bias[col] + res[o];
                }
            }
        }
    }
}

// ---------------------------------------------------------------------------
// Depthwise conv (K=4, pad 1 left / 2 right) + SiLU on both halves of xz.
// xz: (b,l,1024) fp32.  Writes xh fp32 + bf16, and zh bf16 into outbuf[:,512:].
// ---------------------------------------------------------------------------
__global__ __launch_bounds__(256) void conv_silu(
    const float* __restrict__ xz, const float* __restrict__ cwx,
    const float* __restrict__ cwz, float* __restrict__ xh_f,
    unsigned short* __restrict__ xh_b, unsigned short* __restrict__ outbuf)
{
    int idx = blockIdx.x * 256 + threadIdx.x;   // (b*L + l)*512 + d
    int d = idx & 511;
    int bl = idx >> 9;
    int l = bl & (LSEQ - 1);
    float ax = 0.f, az = 0.f;
    #pragma unroll
    for (int k = 0; k < 4; k++) {
        int ll = l + k - 1;
        if (ll >= 0 && ll < LSEQ) {
            const float* src = xz + (size_t)(bl + k - 1) * DINNER;
            ax += cwx[d * 4 + k] * src[d];
            az += cwz[d * 4 + k] * src[512 + d];
        }
    }
    ax = ax / (1.f + __expf(-ax));
    az = az / (1.f + __expf(-az));
    xh_f[idx] = ax;
    xh_b[idx] = f2bf(ax);
    outbuf[(size_t)bl * DINNER + 512 + d] = f2bf(az);
}

// ---------------------------------------------------------------------------
// Selective scan, 3-phase chunked linear recurrence.
// h_l[n] = exp(delta_l*A[n]) * h_{l-1}[n] + delta_l*u_l*B_l[n]
// Chunk decay P[n] = exp(A[n] * sum(delta over chunk)) (closed form).
// ---------------------------------------------------------------------------
__global__ __launch_bounds__(256) void scan_phase1(
    const float* __restrict__ delta, const float* __restrict__ u,
    const float* __restrict__ xdbl, const float* __restrict__ A_log,
    float* __restrict__ S, float* __restrict__ P)
{
    int bx = blockIdx.x;                 // 8 b * 16 c * 2 halves = 256
    int b = bx >> 5, rem = bx & 31, c = rem >> 1, half = rem & 1;
    int d = half * 256 + threadIdx.x;
    float A[NSTATE], h[NSTATE];
    #pragma unroll
    for (int n = 0; n < NSTATE; n++) {
        A[n] = -__expf(A_log[d * NSTATE + n]);
        h[n] = 0.f;
    }
    float sdt = 0.f;
    int l0 = c * LCHUNK;
    for (int l = l0; l < l0 + LCHUNK; ++l) {
        size_t idx = (size_t)(b * LSEQ + l);
        float dv = delta[idx * D2 + d];
        float uv = u[idx * D2 + d];
        float du = dv * uv;
        const float4* Bp = (const float4*)(xdbl + idx * 64 + 32);
        float4 B0 = Bp[0], B1 = Bp[1], B2 = Bp[2], B3 = Bp[3];
        float Bn[16] = {B0.x, B0.y, B0.z, B0.w, B1.x, B1.y, B1.z, B1.w,
                        B2.x, B2.y, B2.z, B2.w, B3.x, B3.y, B3.z, B3.w};
        sdt += dv;
        #pragma unroll
        for (int n = 0; n < NSTATE; n++)
            h[n] = __expf(dv * A[n]) * h[n] + du * Bn[n];
    }
    size_t o = ((size_t)(b * D2 + d)) * (NCHUNK * NSTATE) + c * NSTATE;
    #pragma unroll
    for (int n = 0; n < NSTATE; n++) {
        S[o + n] = h[n];
        P[o + n] = __expf(sdt * A[n]);
    }
}

__global__ __launch_bounds__(256) void scan_phase2(
    const float* __restrict__ S, const float* __restrict__ P,
    float* __restrict__ hin)
{
    int gid = blockIdx.x * 256 + threadIdx.x;   // 65536 = 8*512*16
    int n = gid & 15, d = (gid >> 4) & 511, b = gid >> 13;
    size_t base = ((size_t)(b * D2 + d)) * (NCHUNK * NSTATE) + n;
    float h = 0.f;
    for (int c = 0; c < NCHUNK; c++) {
        size_t o = base + c * NSTATE;
        hin[o] = h;
        h = P[o] * h + S[o];
    }
}

__global__ __launch_bounds__(256) void scan_phase3(
    const float* __restrict__ delta, const float* __restrict__ u,
    const float* __restrict__ xdbl, const float* __restrict__ hin,
    const float* __restrict__ A_log, const float* __restrict__ Dvec,
    unsigned short* __restrict__ outbuf)
{
    int bx = blockIdx.x;
    int b = bx >> 5, rem = bx & 31, c = rem >> 1, half = rem & 1;
    int d = half * 256 + threadIdx.x;
    float A[NSTATE], h[NSTATE];
    size_t hb = ((size_t)(b * D2 + d)) * (NCHUNK * NSTATE) + c * NSTATE;
    #pragma unroll
    for (int n = 0; n < NSTATE; n++) {
        A[n] = -__expf(A_log[d * NSTATE + n]);
        h[n] = hin[hb + n];
    }
    float Dd = Dvec[d];
    int l0 = c * LCHUNK;
    for (int l = l0; l < l0 + LCHUNK; ++l) {
        size_t idx = (size_t)(b * LSEQ + l);
        float dv = delta[idx * D2 + d];
        float uv = u[idx * D2 + d];
        float du = dv * uv;
        const float4* Bp = (const float4*)(xdbl + idx * 64 + 32);
        const float4* Cp = (const float4*)(xdbl + idx * 64 + 48);
        float4 B0 = Bp[0], B1 = Bp[1], B2 = Bp[2], B3 = Bp[3];
        float4 C0 = Cp[0], C1 = Cp[1], C2 = Cp[2], C3 = Cp[3];
        float Bn[16] = {B0.x, B0.y, B0.z, B0.w, B1.x, B1.y, B1.z, B1.w,
                        B2.x, B2.y, B2.z, B2.w, B3.x, B3.y, B3.z, B3.w};
        float Cn[16] = {C0.x, C0.y, C0.z, C0.w, C1.x, C1.y, C1.z, C1.w,
                        C2.x, C2.y, C2.z, C2.w, C3.x, C3.y, C3.z, C3.w};
        float y = Dd * uv;
        #pragma unroll
        for (int n = 0; n < NSTATE; n++) {
            h[n] = __expf(dv * A[n]) * h[n] + du * Bn[n];
            y += h[n] * Cn[n];
        }
        outbuf[idx * DINNER + d] = f2bf(y);
    }
}

// ---------------------------------------------------------------------------
// Host-side launch
// ---------------------------------------------------------------------------
extern "C" void kernel_launch(void* const* d_in, const int* in_sizes, int n_in,
                              void* d_out, int out_size, void* d_ws, size_t ws_size,
                              hipStream_t stream)
{
    const float* x         = (const float*)d_in[0];
    const float* ln1_w     = (const float*)d_in[1];
    const float* ln1_b     = (const float*)d_in[2];
    const float* in_proj_w = (const float*)d_in[3];
    const float* conv_x_w  = (const float*)d_in[4];
    const float* conv_z_w  = (const float*)d_in[5];
    const float* x_proj_w  = (const float*)d_in[6];
    const float* dt_proj_w = (const float*)d_in[7];
    const float* dt_proj_b = (const float*)d_in[8];
    const float* A_log     = (const float*)d_in[9];
    const float* ssm_D     = (const float*)d_in[10];
    const float* out_proj_w= (const float*)d_in[11];
    const float* ln2_w     = (const float*)d_in[12];
    const float* ln2_b     = (const float*)d_in[13];
    const float* fc1_w     = (const float*)d_in[14];
    const float* fc1_b     = (const float*)d_in[15];
    const float* fc2_w     = (const float*)d_in[16];
    const float* fc2_b     = (const float*)d_in[17];
    float* out = (float*)d_out;

    // ---- workspace layout (bytes) ----
    char* p = (char*)d_ws;
    unsigned short* wbf_inproj  = (unsigned short*)(p);              // 1,048,576
    unsigned short* wbf_xproj   = (unsigned short*)(p + 1048576);    //    65,536
    unsigned short* wbf_dtproj  = (unsigned short*)(p + 1114112);    //    32,768
    unsigned short* wbf_outproj = (unsigned short*)(p + 1146880);    // 1,048,576
    unsigned short* wbf_fc1     = (unsigned short*)(p + 2195456);    // 2,097,152
    unsigned short* wbf_fc2     = (unsigned short*)(p + 4292608);    // 2,097,152
    char* dyn = p + 6389760;
    unsigned short* xn_bf   = (unsigned short*)(dyn);                 // 8,388,608 (reused as h2)
    float*          xz_f32  = (float*)(dyn + 8388608);                // 33,554,432 (reused as mlp1 bf16)
    float*          xh_f32  = (float*)(dyn + 41943040);               // 16,777,216
    unsigned short* xh_bf   = (unsigned short*)(dyn + 58720256);      // 8,388,608 (reused as scan S|P)
    unsigned short* outbuf  = (unsigned short*)(dyn + 67108864);      // 16,777,216
    float*          xdbl_f32= (float*)(dyn + 83886080);               // 2,097,152
    unsigned short* xdbl_bf = (unsigned short*)(dyn + 85983232);      // 1,048,576
    float*          delta_f = (float*)(dyn + 87031808);               // 16,777,216
    float*          hin     = (float*)(dyn + 103809024);              // 4,194,304
    float*          h_f32   = (float*)(dyn + 108003328);              // 16,777,216
    // scan S/P overlay xh_bf region (dead after x_proj GEMM)
    float* scanS = (float*)(dyn + 58720256);                          // 4,194,304
    float* scanP = (float*)(dyn + 62914560);                          // 4,194,304
    unsigned short* h2_bf   = xn_bf;                                  // overlay
    unsigned short* mlp1_bf = (unsigned short*)xz_f32;                // overlay

    // 1. weights -> bf16
    cvt_weights<<<12480, 256, 0, stream>>>(in_proj_w, x_proj_w, dt_proj_w,
        out_proj_w, fc1_w, fc2_w, wbf_inproj, wbf_xproj, wbf_dtproj,
        wbf_outproj, wbf_fc1, wbf_fc2);

    // 2. LN1
    ln_kernel<<<MROWS, 256, 0, stream>>>(x, ln1_w, ln1_b, xn_bf);

    // 3. in_proj: xz = xn @ W^T  (8192 x 1024, K=512)
    gemm_bf16<M_F32><<<dim3(64, 8), 256, 0, stream>>>(
        xn_bf, DMODEL, wbf_inproj, DMODEL, MROWS, DINNER, DMODEL,
        xz_f32, nullptr, DINNER, nullptr, nullptr);

    // 4. depthwise conv + SiLU
    conv_silu<<<16384, 256, 0, stream>>>(xz_f32, conv_x_w, conv_z_w,
        xh_f32, xh_bf, outbuf);

    // 5. x_proj: x_dbl = xh @ W^T  (8192 x 64, K=512) -> fp32 + bf16
    gemm_bf16<M_F32_BF16><<<dim3(64, 1), 256, 0, stream>>>(
        xh_bf, D2, wbf_xproj, D2, MROWS, 64, D2,
        xdbl_f32, xdbl_bf, 64, nullptr, nullptr);

    // 6. dt_proj + softplus: delta = softplus(dt @ W^T + b)  (8192 x 512, K=32)
    gemm_bf16<M_SOFTPLUS_F32><<<dim3(64, 4), 256, 0, stream>>>(
        xdbl_bf, 64, wbf_dtproj, 32, MROWS, D2, 32,
        delta_f, nullptr, D2, dt_proj_b, nullptr);

    // 7-9. selective scan
    scan_phase1<<<256, 256, 0, stream>>>(delta_f, xh_f32, xdbl_f32, A_log,
        scanS, scanP);
    scan_phase2<<<256, 256, 0, stream>>>(scanS, scanP, hin);
    scan_phase3<<<256, 256, 0, stream>>>(delta_f, xh_f32, xdbl_f32, hin,
        A_log, ssm_D, outbuf);

    // 10. out_proj + residual: h = x + outbuf @ W^T  (8192 x 512, K=1024)
    gemm_bf16<M_RES_F32><<<dim3(64, 4), 256, 0, stream>>>(
        outbuf, DINNER, wbf_outproj, DINNER, MROWS, DMODEL, DINNER,
        h_f32, nullptr, DMODEL, nullptr, x);

    // 11. LN2
    ln_kernel<<<MROWS, 256, 0, stream>>>(h_f32, ln2_w, ln2_b, h2_bf);

    // 12. fc1 + bias + exact GELU -> bf16  (8192 x 2048, K=512)
    gemm_bf16<M_GELU_BF16><<<dim3(64, 16), 256, 0, stream>>>(
        h2_bf, DMODEL, wbf_fc1, DMODEL, MROWS, HIDDEN, DMODEL,
        nullptr, mlp1_bf, HIDDEN, fc1_b, nullptr);

    // 13. fc2 + bias + residual -> d_out  (8192 x 512, K=2048)
    gemm_bf16<M_BIAS_RES_F32><<<dim3(64, 4), 256, 0, stream>>>(
        mlp1_bf, HIDDEN, wbf_fc2, HIDDEN, MROWS, DMODEL, HIDDEN,
        out, nullptr, DMODEL, fc2_b, h_f32);
}